// Round 8
// baseline (769.178 us; speedup 1.0000x reference)
//
#include <hip/hip_runtime.h>
#include <math.h>

#define Bb 2
#define Tt 1024
#define Cc 1024
#define Hh 16
#define Dd 64
#define Mm (Bb*Tt)
#define DECAY_SCALE (-0.6065306597126334f)
#define GN_EPS (64e-5f)

typedef __attribute__((ext_vector_type(8))) short short8;   // 8 bf16 (4 VGPRs)
typedef __attribute__((ext_vector_type(4))) float f32x4;    // MFMA acc

struct GemmDesc {
  const float* A;      // row stride = K
  const float* W;      // (N, K) row-major
  float* out;          // (M, N) row-major
  const float* bias;   // per-n bias or nullptr
  int N, K;
  int mixrow;          // unused in this round (-1)
  int ep;              // 0 none, 1 tanh, 2 sigmoid(x+bias?), 3 DECAY*sigmoid(x+bias)
};

// MFMA GEMM descriptor: pre-split bf16 planes on both sides.
struct MDesc {
  const unsigned short *AH, *AL;   // activation hi/lo planes, (M,1024)
  const unsigned short *WH, *WL;   // weight hi/lo planes, (N,1024)
  float* out;                      // (M,N) fp32
  int N;                           // K fixed = 1024
  int ep;                          // 0 none, 1 tanh, 2 sigmoid
};

__device__ __forceinline__ float4 ld4(const float* p){ return *reinterpret_cast<const float4*>(p); }
__device__ __forceinline__ float sigmf(float x){ return 1.f/(1.f+expf(-x)); }

__device__ __forceinline__ float wredsum(float x){
  #pragma unroll
  for (int off=32; off>0; off>>=1) x += __shfl_xor(x, off);
  return x;
}

// 16-lane sum (lanes 16k..16k+15), pure DPP.
__device__ __forceinline__ float dsum16(float x){
  x += __int_as_float(__builtin_amdgcn_update_dpp(0, __float_as_int(x), 0xB1, 0xF, 0xF, true));
  x += __int_as_float(__builtin_amdgcn_update_dpp(0, __float_as_int(x), 0x4E, 0xF, 0xF, true));
  x += __int_as_float(__builtin_amdgcn_update_dpp(0, __float_as_int(x), 0x141, 0xF, 0xF, true));
  x += __int_as_float(__builtin_amdgcn_update_dpp(0, __float_as_int(x), 0x140, 0xF, 0xF, true));
  return x;
}

// async global -> LDS DMA; dest = wave-uniform base + lane*size
__device__ __forceinline__ void gl2lds16(const float* g, float* l){
  __builtin_amdgcn_global_load_lds(
      (const __attribute__((address_space(1))) unsigned int*)g,
      (__attribute__((address_space(3))) unsigned int*)l, 16, 0, 0);
}
__device__ __forceinline__ void gl2lds4(const float* g, float* l){
  __builtin_amdgcn_global_load_lds(
      (const __attribute__((address_space(1))) unsigned int*)g,
      (__attribute__((address_space(3))) unsigned int*)l, 4, 0, 0);
}

// split fp32 -> (hi bf16 trunc, lo bf16 of remainder), packed 2-at-a-time
__device__ __forceinline__ void split2(float a, float b, unsigned& hw, unsigned& lw){
  unsigned u0 = __float_as_uint(a);
  unsigned u1 = __float_as_uint(b);
  float l0 = a - __uint_as_float(u0 & 0xFFFF0000u);
  float l1 = b - __uint_as_float(u1 & 0xFFFF0000u);
  hw = (u0>>16) | (u1 & 0xFFFF0000u);
  lw = (__float_as_uint(l0)>>16) | (__float_as_uint(l1) & 0xFFFF0000u);
}

// ---------------- vector-ALU GEMM (LoRA stage-2 only) ----------------
#define BM 64
#define BN 128
#define BK 32

__global__ __launch_bounds__(256) void gemm_kernel(
    GemmDesc d0, GemmDesc d1, GemmDesc d2, GemmDesc d3)
{
  GemmDesc d = (blockIdx.z==0)?d0:(blockIdx.z==1)?d1:(blockIdx.z==2)?d2:d3;
  const int n0 = blockIdx.x * BN;
  if (n0 >= d.N) return;
  const int m0 = blockIdx.y * BM;
  const int tid = threadIdx.x;
  __shared__ float As[BK][BM+4];
  __shared__ float Bs[BK][BN+4];
  const int ty = tid >> 4, tx = tid & 15;

  float acc[4][8];
  #pragma unroll
  for (int i=0;i<4;++i)
    #pragma unroll
    for (int j=0;j<8;++j) acc[i][j]=0.f;

  const int K = d.K;
  const int nt = K / BK;
  float4 pa[2], pb[4];

  auto load_tile = [&](int kt){
    const int kbase = kt * BK;
    #pragma unroll
    for (int u=0;u<2;++u){
      const int li = tid + u*256;
      const int ar = li >> 3;
      const int kk = ((li & 7) << 2) + kbase;
      pa[u] = ld4(d.A + (size_t)(m0+ar)*K + kk);
    }
    #pragma unroll
    for (int u=0;u<4;++u){
      const int li = tid + u*256;
      const int br = li >> 3;
      const int kk = ((li & 7) << 2) + kbase;
      const int gn = n0 + br;
      pb[u] = (gn < d.N) ? ld4(d.W + (size_t)gn*K + kk) : make_float4(0.f,0.f,0.f,0.f);
    }
  };

  load_tile(0);
  for (int kt=0; kt<nt; ++kt){
    __syncthreads();
    #pragma unroll
    for (int u=0;u<2;++u){
      const int li = tid + u*256;
      const int ar = li >> 3;
      const int kc = (li & 7) << 2;
      As[kc+0][ar] = pa[u].x; As[kc+1][ar] = pa[u].y;
      As[kc+2][ar] = pa[u].z; As[kc+3][ar] = pa[u].w;
    }
    #pragma unroll
    for (int u=0;u<4;++u){
      const int li = tid + u*256;
      const int br = li >> 3;
      const int kc = (li & 7) << 2;
      Bs[kc+0][br] = pb[u].x; Bs[kc+1][br] = pb[u].y;
      Bs[kc+2][br] = pb[u].z; Bs[kc+3][br] = pb[u].w;
    }
    __syncthreads();
    if (kt+1 < nt) load_tile(kt+1);
    #pragma unroll
    for (int kk=0;kk<BK;++kk){
      const float4 a0 = *(const float4*)&As[kk][ty<<2];
      const float4 b0 = *(const float4*)&Bs[kk][tx<<3];
      const float4 b1 = *(const float4*)&Bs[kk][(tx<<3)+4];
      const float av[4] = {a0.x,a0.y,a0.z,a0.w};
      const float bv[8] = {b0.x,b0.y,b0.z,b0.w,b1.x,b1.y,b1.z,b1.w};
      #pragma unroll
      for (int i=0;i<4;++i)
        #pragma unroll
        for (int j=0;j<8;++j)
          acc[i][j] = fmaf(av[i], bv[j], acc[i][j]);
    }
  }

  const int ep = d.ep;
  #pragma unroll
  for (int i=0;i<4;++i){
    const int gm = m0 + (ty<<2) + i;
    float* orow = d.out + (size_t)gm * d.N;
    #pragma unroll
    for (int j=0;j<8;++j){
      const int gn = n0 + (tx<<3) + j;
      if (gn < d.N){
        float x = acc[i][j];
        if (ep==1) x = tanhf(x);
        else if (ep==2){ if (d.bias) x += d.bias[gn]; x = sigmf(x); }
        else if (ep==3){ x += d.bias[gn]; x = DECAY_SCALE * sigmf(x); }
        orow[gn] = x;
      }
    }
  }
}

// ---------------- weight split (big W planes) ----------------
#define NPL (Cc*Cc)
__global__ __launch_bounds__(256) void wsplit_kernel(
    const float* __restrict__ s0, const float* __restrict__ s1,
    const float* __restrict__ s2, const float* __restrict__ s3,
    unsigned short* __restrict__ planes)
{
  const int z = blockIdx.z;
  const float* src = z==0?s0:z==1?s1:z==2?s2:s3;
  unsigned short* dh = planes + (size_t)z*2*NPL;
  unsigned short* dl = dh + NPL;
  const size_t i = ((size_t)blockIdx.x*256 + threadIdx.x)*4;
  float4 v = ld4(src + i);
  unsigned h0,l0,h1,l1;
  split2(v.x, v.y, h0, l0);
  split2(v.z, v.w, h1, l1);
  uint2 hv; hv.x=h0; hv.y=h1;
  uint2 lv; lv.x=l0; lv.y=l1;
  *(uint2*)(dh + i) = hv;
  *(uint2*)(dl + i) = lv;
}

// ---------------- LoRA A-matrix split (352 rows x 1024, concat w|a|v|g) ----------------
#define LR 352
__global__ __launch_bounds__(256) void lora_split(
    const float* __restrict__ wA, const float* __restrict__ aA,
    const float* __restrict__ vA, const float* __restrict__ gA,
    unsigned short* __restrict__ LP)
{
  const size_t i = ((size_t)blockIdx.x*256 + threadIdx.x)*4;
  const int row = (int)(i >> 10);
  const int col = (int)(i & 1023);
  const float* src; int srow;
  if (row < 64)       { src = wA; srow = row; }
  else if (row < 128) { src = aA; srow = row-64; }
  else if (row < 192) { src = vA; srow = row-128; }
  else                { src = gA; srow = row-192; }
  float4 v = ld4(src + (size_t)srow*1024 + col);
  unsigned h0,l0,h1,l1;
  split2(v.x, v.y, h0, l0);
  split2(v.z, v.w, h1, l1);
  uint2 hv; hv.x=h0; hv.y=h1;
  uint2 lv; lv.x=l0; lv.y=l1;
  *(uint2*)(LP + i) = hv;
  *(uint2*)(LP + (size_t)LR*1024 + i) = lv;
}

// ---------------- token-shift mix -> 6 bf16 hi/lo activation planes ----------------
#define MCu ((size_t)Mm*Cc)
__global__ __launch_bounds__(256) void mix_split(
    const float* __restrict__ hs, const float* __restrict__ xmix,
    unsigned short* __restrict__ XP)
{
  const int m = blockIdx.x;
  const int c = threadIdx.x * 4;
  float4 h0 = ld4(hs + (size_t)m*Cc + c);
  float4 hp = make_float4(0.f,0.f,0.f,0.f);
  if (m & (Tt-1)) hp = ld4(hs + (size_t)(m-1)*Cc + c);
  const float dx = hp.x - h0.x, dy = hp.y - h0.y, dz = hp.z - h0.z, dw = hp.w - h0.w;
  #pragma unroll
  for (int i=0;i<6;++i){
    float4 mx = ld4(xmix + i*Cc + c);
    float xs0 = h0.x + dx*mx.x, xs1 = h0.y + dy*mx.y;
    float xs2 = h0.z + dz*mx.z, xs3 = h0.w + dw*mx.w;
    unsigned hw0,lw0,hw1,lw1;
    split2(xs0, xs1, hw0, lw0);
    split2(xs2, xs3, hw1, lw1);
    unsigned short* dh = XP + (size_t)i*2*MCu + (size_t)m*Cc + c;
    uint2 hv; hv.x=hw0; hv.y=hw1;
    uint2 lv; lv.x=lw0; lv.y=lw1;
    *(uint2*)dh = hv;
    *(uint2*)(dh + MCu) = lv;
  }
}

// ---------------- split-bf16 MFMA GEMM v2 (pre-split planes both sides) ----------------
#define TM 128
#define TN 128
#define LDBS 40   // bf16 row stride in LDS

__global__ __launch_bounds__(256) void gemm_mfma2(
    MDesc d0, MDesc d1, MDesc d2, MDesc d3)
{
  const int z = blockIdx.z;
  MDesc d = z==0?d0:(z==1?d1:(z==2?d2:d3));
  const int n0 = blockIdx.x * TN;
  if (n0 >= d.N) return;
  const int m0 = blockIdx.y * TM;
  const int tid = threadIdx.x;

  __shared__ __align__(16) unsigned short Ah[TM*LDBS], Al[TM*LDBS];
  __shared__ __align__(16) unsigned short Bh[TN*LDBS], Bl[TN*LDBS];

  const int sr = tid >> 1;
  const int sk = (tid & 1) << 4;
  const size_t arow = (size_t)(m0 + sr) * 1024;
  int gn = n0 + sr; if (gn >= d.N) gn = d.N - 1;   // clamp (garbage cols are write-guarded)
  const size_t brow = (size_t)gn * 1024;

  uint4 pah[2], pal[2], pbh[2], pbl[2];
  auto load_slab = [&](int kt){
    const int kb = kt*32 + sk;
    pah[0] = *(const uint4*)(d.AH + arow + kb);
    pah[1] = *(const uint4*)(d.AH + arow + kb + 8);
    pal[0] = *(const uint4*)(d.AL + arow + kb);
    pal[1] = *(const uint4*)(d.AL + arow + kb + 8);
    pbh[0] = *(const uint4*)(d.WH + brow + kb);
    pbh[1] = *(const uint4*)(d.WH + brow + kb + 8);
    pbl[0] = *(const uint4*)(d.WL + brow + kb);
    pbl[1] = *(const uint4*)(d.WL + brow + kb + 8);
  };

  const int wv = tid >> 6, lane = tid & 63;
  const int wm = (wv >> 1) << 6, wn = (wv & 1) << 6;
  const int fr = lane & 15;
  const int fk = (lane >> 4) << 3;

  f32x4 acc[4][4];
  const f32x4 z4 = {0.f,0.f,0.f,0.f};
  #pragma unroll
  for (int i=0;i<4;++i)
    #pragma unroll
    for (int j=0;j<4;++j) acc[i][j]=z4;

  const int nslab = 1024 >> 5;
  load_slab(0);
  for (int kt=0; kt<nslab; ++kt){
    __syncthreads();
    *(uint4*)&Ah[sr*LDBS+sk]   = pah[0];
    *(uint4*)&Ah[sr*LDBS+sk+8] = pah[1];
    *(uint4*)&Al[sr*LDBS+sk]   = pal[0];
    *(uint4*)&Al[sr*LDBS+sk+8] = pal[1];
    *(uint4*)&Bh[sr*LDBS+sk]   = pbh[0];
    *(uint4*)&Bh[sr*LDBS+sk+8] = pbh[1];
    *(uint4*)&Bl[sr*LDBS+sk]   = pbl[0];
    *(uint4*)&Bl[sr*LDBS+sk+8] = pbl[1];
    __syncthreads();
    if (kt+1 < nslab) load_slab(kt+1);

    short8 bh4[4], bl4[4];
    #pragma unroll
    for (int nt=0;nt<4;++nt){
      bh4[nt] = *(const short8*)&Bh[(wn + nt*16 + fr)*LDBS + fk];
      bl4[nt] = *(const short8*)&Bl[(wn + nt*16 + fr)*LDBS + fk];
    }
    #pragma unroll
    for (int mt=0;mt<4;++mt){
      const short8 ah = *(const short8*)&Ah[(wm + mt*16 + fr)*LDBS + fk];
      const short8 al = *(const short8*)&Al[(wm + mt*16 + fr)*LDBS + fk];
      #pragma unroll
      for (int nt=0;nt<4;++nt)
        acc[mt][nt] = __builtin_amdgcn_mfma_f32_16x16x32_bf16(ah, bh4[nt], acc[mt][nt], 0,0,0);
      #pragma unroll
      for (int nt=0;nt<4;++nt)
        acc[mt][nt] = __builtin_amdgcn_mfma_f32_16x16x32_bf16(ah, bl4[nt], acc[mt][nt], 0,0,0);
      #pragma unroll
      for (int nt=0;nt<4;++nt)
        acc[mt][nt] = __builtin_amdgcn_mfma_f32_16x16x32_bf16(al, bh4[nt], acc[mt][nt], 0,0,0);
    }
  }

  // C/D: col = lane&15 (n), row = (lane>>4)*4 + reg (m)
  const int ep = d.ep;
  #pragma unroll
  for (int mt=0;mt<4;++mt){
    #pragma unroll
    for (int nt=0;nt<4;++nt){
      #pragma unroll
      for (int r=0;r<4;++r){
        const int row = wm + mt*16 + ((lane>>4)<<2) + r;
        const int col = wn + nt*16 + fr;
        if (n0 + col < d.N){
          float x = acc[mt][nt][r];
          if (ep==1) x = tanhf(x);
          else if (ep==2) x = sigmf(x);
          d.out[(size_t)(m0+row)*d.N + n0 + col] = x;
        }
      }
    }
  }
}

// ---------------- per-head prep (in-place coefficient precompute) ----------------
__global__ __launch_bounds__(256) void head_prep(
    float* kbuf, float* awbuf, float* svwbuf, float* wbbuf, float* vbuf,
    const float* __restrict__ vfirst,
    const float* __restrict__ k_k, const float* __restrict__ k_a)
{
  const int gid = blockIdx.x*4 + (threadIdx.x>>6);
  const int e = threadIdx.x & 63;
  const int m = gid >> 4;
  const int h = gid & 15;
  const int c = h*Dd + e;
  const size_t idx = (size_t)m*Cc + c;
  const float kv0 = kbuf[idx];
  const float av  = awbuf[idx];
  const float sv  = svwbuf[idx];
  const float wv  = wbbuf[idx];
  const float v0  = vbuf[idx];
  const float vf  = vfirst[idx];
  const float kku = kv0 * k_k[c];
  const float ss  = wredsum(kku*kku);
  const float kkn = kku / fmaxf(sqrtf(ss), 1e-12f);
  const float ew  = expf(wv);
  kbuf[idx]  = kv0 * (1.f + (av - 1.f)*k_a[c]);
  awbuf[idx] = ew;
  svwbuf[idx]= -kkn * ew;
  wbbuf[idx] = kkn * av;
  vbuf[idx]  = v0 + sv*(vf - v0);
}

// ---------------- sequential scan v8 (unchanged from R7: 163 us) ----------------
#define NB (Tt/16)
__global__ __launch_bounds__(64) void scan_kernel(
    const float* __restrict__ lawb, const float* __restrict__ ewb,
    const float* __restrict__ bbb,  const float* __restrict__ kb,
    const float* __restrict__ rb,   const float* __restrict__ vb,
    float* __restrict__ outp)
{
  const int blk  = blockIdx.x;
  const int bh   = blk & 31;
  const int blkc = blk >> 5;
  const int b = bh >> 4, h = bh & 15;
  const int lane = threadIdx.x;
  const int es = lane >> 4;
  const int rd = lane & 15;
  const int colb = blkc * 4;
  const int hb = h * Dd;
  const int la = 4*rd;

  __shared__ __align__(16) float LB[2][5*1024 + 64];

  float S0=0.f, S1=0.f, S2=0.f, S3=0.f;
  const size_t mbase = (size_t)b*Tt;

  const int qrow = lane >> 4;
  const int qcol = (lane & 15) * 4;

  auto stage = [&](int bt){
    const size_t g0 = (mbase + (size_t)bt*16)*Cc + hb;
    float* dst = &LB[bt&1][0];
    const float* srcs[5] = {lawb, ewb, bbb, kb, rb};
    #pragma unroll
    for (int a=0;a<5;++a){
      const float* s = srcs[a] + g0 + (size_t)qrow*Cc + qcol;
      #pragma unroll
      for (int i=0;i<4;++i)
        gl2lds16(s + (size_t)(4*i)*Cc, dst + a*1024 + i*256);
    }
    gl2lds4(vb + g0 + (size_t)(lane>>2)*Cc + colb + (lane&3), dst + 5120);
  };

  stage(0);

  for (int bt = 0; bt < NB; ++bt){
    __builtin_amdgcn_s_waitcnt(0x0F70);   // vmcnt(0)
    if (bt+1 < NB) stage(bt+1);
    const float* cb2 = &LB[bt&1][0];

    float4 LwA,EwA,BqA,KqA,RqA, LwB,EwB,BqB,KqB,RqB;
    float VvA, VvB;
    auto ldq = [&](int t, float4&Lw, float4&Ew, float4&Bq, float4&Kq, float4&Rq, float&Vv){
      Lw = *(const float4*)&cb2[         t*64 + la];
      Ew = *(const float4*)&cb2[1024 + t*64 + la];
      Bq = *(const float4*)&cb2[2048 + t*64 + la];
      Kq = *(const float4*)&cb2[3072 + t*64 + la];
      Rq = *(const float4*)&cb2[4096 + t*64 + la];
      Vv = cb2[5120 + t*4 + es];
    };
    ldq(0, LwA,EwA,BqA,KqA,RqA,VvA);
    ldq(1, LwB,EwB,BqB,KqB,RqB,VvB);

    auto stepf = [&](int t, float4&Lw, float4&Ew, float4&Bq, float4&Kq, float4&Rq, float&Vv){
      const float4 rr = Rq;
      const float vv = Vv;
      float ta = fmaf(Lw.y, S1, Lw.x*S0);
      float tb = fmaf(Lw.w, S3, Lw.z*S2);
      ta = dsum16(ta + tb);
      S0 = fmaf(Ew.x, S0, fmaf(Bq.x, ta, Kq.x*vv));
      S1 = fmaf(Ew.y, S1, fmaf(Bq.y, ta, Kq.y*vv));
      S2 = fmaf(Ew.z, S2, fmaf(Bq.z, ta, Kq.z*vv));
      S3 = fmaf(Ew.w, S3, fmaf(Bq.w, ta, Kq.w*vv));
      if (t+2 < 16) ldq(t+2, Lw,Ew,Bq,Kq,Rq,Vv);
      float oe = fmaf(rr.y, S1, rr.x*S0);
      float ob = fmaf(rr.w, S3, rr.z*S2);
      oe = dsum16(oe + ob);
      if (rd == 0)
        outp[(mbase + (size_t)(bt*16 + t))*Cc + hb + colb + es] = oe;
    };

    #pragma unroll
    for (int t = 0; t < 16; ++t){
      if (t & 1) stepf(t, LwB,EwB,BqB,KqB,RqB,VvB);
      else       stepf(t, LwA,EwA,BqA,KqA,RqA,VvA);
    }
  }
}

// ---------------- GroupNorm + correction + g gating -> o_pre bf16 hi/lo planes ----------------
__global__ __launch_bounds__(256) void epilogue_kernel(
    const float* __restrict__ att, const float* __restrict__ rbuf,
    const float* __restrict__ kbuf, const float* __restrict__ vbuf,
    const float* __restrict__ gbuf,
    const float* __restrict__ r_k, const float* __restrict__ gn_w,
    const float* __restrict__ gn_b,
    unsigned short* __restrict__ oph, unsigned short* __restrict__ opl)
{
  const int gid = blockIdx.x*4 + (threadIdx.x>>6);
  const int e = threadIdx.x & 63;
  const int m = gid >> 4;
  const int h = gid & 15;
  const int c = h*Dd + e;
  const size_t idx = (size_t)m*Cc + c;
  const float x  = att[idx];
  const float mu = wredsum(x) * (1.f/Dd);
  const float xd = x - mu;
  const float var = wredsum(xd*xd) * (1.f/Dd);
  const float og = xd * (1.f/sqrtf(var + GN_EPS)) * gn_w[c] + gn_b[c];
  const float rv = rbuf[idx], kv = kbuf[idx], vv = vbuf[idx];
  const float cd = wredsum(rv*kv*r_k[c]);
  const float op = (og + cd*vv) * gbuf[idx];
  const unsigned u = __float_as_uint(op);
  const float lo = op - __uint_as_float(u & 0xFFFF0000u);
  oph[idx] = (unsigned short)(u >> 16);
  opl[idx] = (unsigned short)(__float_as_uint(lo) >> 16);
}

extern "C" void kernel_launch(void* const* d_in, const int* in_sizes, int n_in,
                              void* d_out, int out_size, void* d_ws, size_t ws_size,
                              hipStream_t stream)
{
  (void)in_sizes; (void)n_in; (void)out_size; (void)ws_size;
  const float* hs     = (const float*)d_in[0];
  const float* vfirst = (const float*)d_in[1];
  const float* xmix   = (const float*)d_in[2];
  const float* k_k    = (const float*)d_in[3];
  const float* k_a    = (const float*)d_in[4];
  const float* r_k    = (const float*)d_in[5];
  const float* W_r    = (const float*)d_in[6];
  const float* W_k    = (const float*)d_in[7];
  const float* W_v    = (const float*)d_in[8];
  const float* W_o    = (const float*)d_in[9];
  const float* w_A    = (const float*)d_in[10];
  const float* w_B    = (const float*)d_in[11];
  const float* w_b    = (const float*)d_in[12];
  const float* a_A    = (const float*)d_in[13];
  const float* a_B    = (const float*)d_in[14];
  const float* a_b    = (const float*)d_in[15];
  const float* v_A    = (const float*)d_in[16];
  const float* v_B    = (const float*)d_in[17];
  const float* v_b    = (const float*)d_in[18];
  const float* g_A    = (const float*)d_in[19];
  const float* g_B    = (const float*)d_in[20];
  const float* gn_w   = (const float*)d_in[21];
  const float* gn_b   = (const float*)d_in[22];
  float* out = (float*)d_out;
  float* ws  = (float*)d_ws;

  const size_t MC = (size_t)Mm * Cc;     // floats per (M,C) buffer
  float* Br   = ws;            // r
  float* Bw   = ws + MC;       // w -> bb -> (epilogue) o_pre bf16 planes
  float* Bk   = ws + 2*MC;     // k0 -> kfin
  float* Bkk  = ws + 3*MC;     // sv -> law
  float* Bv   = ws + 4*MC;     // v0 -> v
  float* Ba   = ws + 5*MC;     // a -> ew
  float* T1w  = ws + 6*MC;
  float* T1a  = T1w + (size_t)Mm*64;
  float* T1v  = T1a + (size_t)Mm*64;
  float* T1g  = T1v + (size_t)Mm*64;             // Mm*160
  unsigned short* WP = (unsigned short*)(ws + 6*MC + (size_t)Mm*352);
  unsigned short* WrH = WP + 0*(size_t)NPL, *WrL = WP + 1*(size_t)NPL;
  unsigned short* WkH = WP + 2*(size_t)NPL, *WkL = WP + 3*(size_t)NPL;
  unsigned short* WvH = WP + 4*(size_t)NPL, *WvL = WP + 5*(size_t)NPL;
  unsigned short* WoH = WP + 6*(size_t)NPL, *WoL = WP + 7*(size_t)NPL;
  unsigned short* LP  = WP + 8*(size_t)NPL;      // 2*LR*1024 ushorts
  unsigned short* XP  = LP + 2*(size_t)LR*1024;  // 6 * 2 * MC ushorts (48 MB)
  // overlays on XP (dead after L2): Batt = planes of mix 0, Bg = planes of mix 1
  float* Batt = (float*)XP;
  float* Bg   = (float*)XP + MC;
  // o_pre planes overlay Bw (dead after scan): 2*MC ushorts = MC floats
  unsigned short* OPH = (unsigned short*)Bw;
  unsigned short* OPL = OPH + MC;

  dim3 blk(256,1,1);

  // L0a: big weight planes
  wsplit_kernel<<<dim3(NPL/(256*4),1,4), blk, 0, stream>>>(W_r, W_k, W_v, W_o, WP);
  // L0b: LoRA A planes (w|a|v|g rows)
  lora_split<<<dim3(LR*1024/(256*4)), blk, 0, stream>>>(w_A, a_A, v_A, g_A, LP);
  // L0c: token-shift mixes -> 6 bf16 hi/lo activation planes
  mix_split<<<dim3(Mm), blk, 0, stream>>>(hs, xmix, XP);

  // plane accessors (mix order: r,w,k,v,a,g = 0..5)
  auto XH = [&](int i){ return XP + (size_t)i*2*MC; };
  auto XL = [&](int i){ return XP + (size_t)i*2*MC + MC; };

  // L1: big projections r, k0, v0 (pure-MFMA)
  MDesc mr{XH(0), XL(0), WrH, WrL, Br, Cc, 0};
  MDesc mk{XH(2), XL(2), WkH, WkL, Bk, Cc, 0};
  MDesc mv{XH(3), XL(3), WvH, WvL, Bv, Cc, 0};
  gemm_mfma2<<<dim3(Cc/TN, Mm/TM, 3), blk, 0, stream>>>(mr, mk, mv, mr);

  // L2: LoRA stage-1 (pure-MFMA; w: tanh, g: sigmoid)
  MDesc lw{XH(1), XL(1), LP + 0,          LP + (size_t)LR*1024 + 0,          T1w, 64, 1};
  MDesc la{XH(4), XL(4), LP + 64*1024,    LP + (size_t)LR*1024 + 64*1024,    T1a, 64, 0};
  MDesc lv{XH(3), XL(3), LP + 128*1024,   LP + (size_t)LR*1024 + 128*1024,   T1v, 64, 0};
  MDesc lg{XH(5), XL(5), LP + 192*1024,   LP + (size_t)LR*1024 + 192*1024,   T1g, 160, 2};
  gemm_mfma2<<<dim3(2, Mm/TM, 4), blk, 0, stream>>>(lw, la, lv, lg);

  // L3: LoRA stage-2 (vector GEMM, K small)
  GemmDesc s2w{T1w, w_B, Bw,  w_b,    Cc, 64,  -1, 3};
  GemmDesc s2a{T1a, a_B, Ba,  a_b,    Cc, 64,  -1, 2};
  GemmDesc s2v{T1v, v_B, Bkk, v_b,    Cc, 64,  -1, 2};
  GemmDesc s2g{T1g, g_B, Bg,  nullptr,Cc, 160, -1, 0};
  gemm_kernel<<<dim3(8,32,4), blk, 0, stream>>>(s2w, s2a, s2v, s2g);

  // L4: per-head prep; in place: Bk k0->kfin, Ba a->ew, Bkk sv->law, Bw w->bb, Bv v0->v
  head_prep<<<dim3(Mm*Hh/4), blk, 0, stream>>>(Bk, Ba, Bkk, Bw, Bv,
                                               vfirst, k_k, k_a);

  // L5: sequential scan (v8)
  scan_kernel<<<dim3(512), dim3(64), 0, stream>>>(Bkk, Ba, Bw, Bk, Br, Bv, Batt);

  // L6: groupnorm + corr + g -> o_pre bf16 planes (overlay Bw)
  epilogue_kernel<<<dim3(Mm*Hh/4), blk, 0, stream>>>(Batt, Br, Bk, Bv, Bg,
                                                     r_k, gn_w, gn_b, OPH, OPL);

  // L7: output projection (pure-MFMA)
  MDesc mo{OPH, OPL, WoH, WoL, out, Cc, 0};
  gemm_mfma2<<<dim3(Cc/TN, Mm/TM, 1), blk, 0, stream>>>(mo, mo, mo, mo);
}